// Round 4
// baseline (76.438 us; speedup 1.0000x reference)
//
#include <hip/hip_runtime.h>
#include <hip/hip_bf16.h>

#define DDIM 4096
#define NROWS 16384
#define SK_ITERS 20
#define KC 256      // K-floats per chunk
#define NCH 16      // DDIM / KC

typedef __attribute__((ext_vector_type(8))) __bf16 bf16x8;
typedef __attribute__((ext_vector_type(4))) float f32x4;
typedef __attribute__((ext_vector_type(4))) int   i32x4;

// Block = 2 waves x 16 token-rows, each wave FULLY independent (full K=4096):
// no barriers anywhere. Per chunk (16 rows x 256 K-floats = 16KB, double-
// buffered), 16 DMA instrs each read 1KB CONTIGUOUS from one row (XOR swizzle
// phys_granule = logical ^ (row&7) applied as a pure lane permutation of the
// same 1KB window -> ideal bursts). W stays fp32, 16 pipelined inline-asm
// dwordx4 per chunk (single-buffered; L2-resident), cvt to bf16 in-loop.
// FIFO per iter: [W_c:16][DMA_{c+1}:16] -> wait vmcnt(16) leaves DMA_{c+1}
// in flight. k-bijection (A and B identical): k = c*256 + st*32 + kq*8 + i.
__global__ __launch_bounds__(128, 1)
void rsm_kernel(const float* __restrict__ x, const float* __restrict__ W,
                const float* __restrict__ bias, const float* __restrict__ alpha_p,
                float* __restrict__ out)
{
    __shared__ __align__(16) float lds[2][2][16][KC];   // 64 KB exactly

    const int tid  = threadIdx.x;
    const int wave = tid >> 6;
    const int lane = tid & 63;
    const int r16  = lane & 15;   // A row-in-tile, W row (output col), C col
    const int kq   = lane >> 4;
    const int z    = r16 & 7;

    const int rowbase = blockIdx.x * 32 + wave * 16;

    // DMA instr j stages row j: LDS[j][g] <- x_row_j[g ^ (j&7)]; the 64 lane
    // addresses are a permutation of one contiguous 1KB window.
    const float* sbase[16];
#pragma unroll
    for (int j = 0; j < 16; ++j)
        sbase[j] = x + (size_t)(rowbase + j) * DDIM + ((lane ^ (j & 7)) << 2);

    const float* wq = W + (size_t)r16 * DDIM + kq * 8;

    i32x4 wr[16];   // current chunk's W fp32 (8 subtiles x 2 dwordx4)

    auto wissue = [&](int c) {
        const float* p = wq + c * KC;
        asm volatile(
            "global_load_dwordx4 %0,  %16, off\n\t"
            "global_load_dwordx4 %1,  %16, off offset:16\n\t"
            "global_load_dwordx4 %2,  %16, off offset:128\n\t"
            "global_load_dwordx4 %3,  %16, off offset:144\n\t"
            "global_load_dwordx4 %4,  %16, off offset:256\n\t"
            "global_load_dwordx4 %5,  %16, off offset:272\n\t"
            "global_load_dwordx4 %6,  %16, off offset:384\n\t"
            "global_load_dwordx4 %7,  %16, off offset:400\n\t"
            "global_load_dwordx4 %8,  %16, off offset:512\n\t"
            "global_load_dwordx4 %9,  %16, off offset:528\n\t"
            "global_load_dwordx4 %10, %16, off offset:640\n\t"
            "global_load_dwordx4 %11, %16, off offset:656\n\t"
            "global_load_dwordx4 %12, %16, off offset:768\n\t"
            "global_load_dwordx4 %13, %16, off offset:784\n\t"
            "global_load_dwordx4 %14, %16, off offset:896\n\t"
            "global_load_dwordx4 %15, %16, off offset:912"
            : "=&v"(wr[0]),  "=&v"(wr[1]),  "=&v"(wr[2]),  "=&v"(wr[3]),
              "=&v"(wr[4]),  "=&v"(wr[5]),  "=&v"(wr[6]),  "=&v"(wr[7]),
              "=&v"(wr[8]),  "=&v"(wr[9]),  "=&v"(wr[10]), "=&v"(wr[11]),
              "=&v"(wr[12]), "=&v"(wr[13]), "=&v"(wr[14]), "=&v"(wr[15])
            : "v"(p));
    };

    auto stage = [&](int c) {
        const int b = c & 1;
#pragma unroll
        for (int j = 0; j < 16; ++j) {
            __builtin_amdgcn_global_load_lds(
                (const __attribute__((address_space(1))) void*)(sbase[j] + c * KC),
                (__attribute__((address_space(3))) void*)(&lds[wave][b][j][0]),
                16, 0, 0);
        }
    };

    stage(0);

    f32x4 acc = {0.f, 0.f, 0.f, 0.f};
    float sumsq = 0.f;

#pragma unroll
    for (int c = 0; c < NCH; ++c) {
        wissue(c);
        if (c + 1 < NCH) stage(c + 1);
        __builtin_amdgcn_sched_barrier(0);
        if (c + 1 < NCH) asm volatile("s_waitcnt vmcnt(16)" ::: "memory");
        else             asm volatile("s_waitcnt vmcnt(0)"  ::: "memory");
        __builtin_amdgcn_sched_barrier(0);

        const float* arow = &lds[wave][c & 1][r16][0];
#pragma unroll
        for (int st = 0; st < 8; ++st) {
            const int g = st * 8 + kq * 2;
            f32x4 a0 = *(const f32x4*)(arow + (((g    ) ^ z) << 2));
            f32x4 a1 = *(const f32x4*)(arow + (((g + 1) ^ z) << 2));

            sumsq += a0[0]*a0[0] + a0[1]*a0[1] + a0[2]*a0[2] + a0[3]*a0[3]
                   + a1[0]*a1[0] + a1[1]*a1[1] + a1[2]*a1[2] + a1[3]*a1[3];

            f32x4 b0 = __builtin_bit_cast(f32x4, wr[st * 2]);
            f32x4 b1 = __builtin_bit_cast(f32x4, wr[st * 2 + 1]);

            bf16x8 af, bv;
            af[0]=(__bf16)a0[0]; af[1]=(__bf16)a0[1]; af[2]=(__bf16)a0[2]; af[3]=(__bf16)a0[3];
            af[4]=(__bf16)a1[0]; af[5]=(__bf16)a1[1]; af[6]=(__bf16)a1[2]; af[7]=(__bf16)a1[3];
            bv[0]=(__bf16)b0[0]; bv[1]=(__bf16)b0[1]; bv[2]=(__bf16)b0[2]; bv[3]=(__bf16)b0[3];
            bv[4]=(__bf16)b1[0]; bv[5]=(__bf16)b1[1]; bv[6]=(__bf16)b1[2]; bv[7]=(__bf16)b1[3];

            acc = __builtin_amdgcn_mfma_f32_16x16x32_bf16(af, bv, acc, 0, 0, 0);
        }
    }

    // ---- epilogue (no LDS, no barriers): RMS scale + 4 parallel Sinkhorns ----
    float s = sumsq;
    s += __shfl_xor(s, 16);
    s += __shfl_xor(s, 32);          // s = S[r16] in every lane

    const float al = alpha_p[0];
    const float bi = bias[r16];

    float m[4];
#pragma unroll
    for (int r = 0; r < 4; ++r) {
        float Srow  = __shfl(s, kq * 4 + r);   // token row of acc[r]
        float scale = rsqrtf(Srow * (1.0f / DDIM) + 1.1920929e-07f);  // fp32 eps
        m[r] = expf(al * (acc[r] * scale) + bi);
    }

    for (int it = 0; it < SK_ITERS; ++it) {
#pragma unroll
        for (int r = 0; r < 4; ++r) {          // col normalize (sum over i = bits 2,3)
            float t = m[r] + __shfl_xor(m[r], 4);
            t += __shfl_xor(t, 8);
            m[r] = m[r] / (t + 1e-8f);
        }
#pragma unroll
        for (int r = 0; r < 4; ++r) {          // row normalize (sum over j = bits 0,1)
            float t = m[r] + __shfl_xor(m[r], 1);
            t += __shfl_xor(t, 2);
            m[r] = m[r] / (t + 1e-8f);
        }
    }

#pragma unroll
    for (int r = 0; r < 4; ++r)
        out[(size_t)(rowbase + kq * 4 + r) * 16 + r16] = m[r];
}

extern "C" void kernel_launch(void* const* d_in, const int* in_sizes, int n_in,
                              void* d_out, int out_size, void* d_ws, size_t ws_size,
                              hipStream_t stream) {
    const float* x     = (const float*)d_in[0];
    const float* W     = (const float*)d_in[1];
    const float* bias  = (const float*)d_in[2];
    const float* alpha = (const float*)d_in[3];
    float* out = (float*)d_out;

    rsm_kernel<<<dim3(NROWS / 32), dim3(128), 0, stream>>>(x, W, bias, alpha, out);
}

// Round 5
// 70.042 us; speedup vs baseline: 1.0913x; 1.0913x over previous
//
#include <hip/hip_runtime.h>
#include <hip/hip_bf16.h>

#define DDIM 4096
#define NROWS 16384
#define SK_ITERS 20
#define KC 256      // K-floats per chunk (per row)
#define NCH 16      // DDIM / KC

typedef __attribute__((ext_vector_type(8))) __bf16 bf16x8;
typedef __attribute__((ext_vector_type(4))) float f32x4;
typedef __attribute__((ext_vector_type(4))) int   i32x4;

// Block = 16 token-rows, 128 threads = 2 waves splitting K WITHIN each chunk
// (wave w computes subtiles st = w*4..w*4+3 of every chunk; partials combined
// in the epilogue). Staging: chunk = 16 rows x 256 floats (16 KB, double-
// buffered, 32 KB LDS -> 4 blocks/CU = 8 waves/CU); each wave DMA-stages 8
// rows with ONE 1KB-contiguous global_load_lds per row (lane-permuted source
// ^ (row&7) at 16B granularity = XOR bank swizzle; linear LDS dest).
// W fp32 rides the same per-wave vmcnt FIFO one group ahead (group g_c =
// [8 W][8 DMA]); waits are counted (vmcnt(16)), barriers are RAW s_barrier
// (no vmcnt(0) drain). k-bijection (A and B identical):
//   k = c*256 + wave*128 + st*32 + kq*8 + i.
__global__ __launch_bounds__(128, 2)
void rsm_kernel(const float* __restrict__ x, const float* __restrict__ W,
                const float* __restrict__ bias, const float* __restrict__ alpha_p,
                float* __restrict__ out)
{
    __shared__ __align__(16) float lds[2][16][KC];   // 32 KB

    const int tid  = threadIdx.x;
    const int wave = tid >> 6;
    const int lane = tid & 63;
    const int r16  = lane & 15;   // A row-in-tile, W row (output col), C col
    const int kq   = lane >> 4;
    const int z    = r16 & 7;
    const int rowbase = blockIdx.x * 16;

    // DMA sources: this wave stages rows wave*8 + jj, 1KB window per instr,
    // lanes permuted by ^ (row&7) (16B granules).
    const float* sbase[8];
#pragma unroll
    for (int jj = 0; jj < 8; ++jj) {
        int row = wave * 8 + jj;
        sbase[jj] = x + (size_t)(rowbase + row) * DDIM + ((lane ^ (row & 7)) << 2);
    }

    const float* wq = W + (size_t)r16 * DDIM + wave * 128 + kq * 8;

    i32x4 wr[2][8];   // W register pipeline, double-buffered (static idx c&1)

    // group g_c = [8 W dwordx4][8 DMA 1KB] = 16 vm ops per wave
    auto issue = [&](int c) {
        const float* p = wq + c * KC;
        i32x4* wd = wr[c & 1];
        asm volatile(
            "global_load_dwordx4 %0, %8, off\n\t"
            "global_load_dwordx4 %1, %8, off offset:16\n\t"
            "global_load_dwordx4 %2, %8, off offset:128\n\t"
            "global_load_dwordx4 %3, %8, off offset:144\n\t"
            "global_load_dwordx4 %4, %8, off offset:256\n\t"
            "global_load_dwordx4 %5, %8, off offset:272\n\t"
            "global_load_dwordx4 %6, %8, off offset:384\n\t"
            "global_load_dwordx4 %7, %8, off offset:400"
            : "=&v"(wd[0]), "=&v"(wd[1]), "=&v"(wd[2]), "=&v"(wd[3]),
              "=&v"(wd[4]), "=&v"(wd[5]), "=&v"(wd[6]), "=&v"(wd[7])
            : "v"(p));
#pragma unroll
        for (int jj = 0; jj < 8; ++jj) {
            __builtin_amdgcn_global_load_lds(
                (const __attribute__((address_space(1))) void*)(sbase[jj] + c * KC),
                (__attribute__((address_space(3))) void*)(&lds[c & 1][wave * 8 + jj][0]),
                16, 0, 0);
        }
    };

    issue(0);
    issue(1);

    f32x4 acc = {0.f, 0.f, 0.f, 0.f};
    float sumsq = 0.f;

#pragma unroll
    for (int c = 0; c < NCH; ++c) {
        // entering: g_c + g_{c+1} outstanding (32 ops) -> wait leaves g_{c+1}
        if (c < NCH - 1) asm volatile("s_waitcnt vmcnt(16)" ::: "memory");
        else             asm volatile("s_waitcnt vmcnt(0)"  ::: "memory");
        __builtin_amdgcn_sched_barrier(0);
        asm volatile("s_barrier" ::: "memory");   // both waves' g_c landed
        __builtin_amdgcn_sched_barrier(0);

        const float* arow = &lds[c & 1][r16][0];
#pragma unroll
        for (int st = 0; st < 4; ++st) {
            const int g0 = wave * 32 + st * 8 + kq * 2;
            f32x4 a0 = *(const f32x4*)(arow + (((g0    ) ^ z) << 2));
            f32x4 a1 = *(const f32x4*)(arow + (((g0 + 1) ^ z) << 2));

            sumsq += a0[0]*a0[0] + a0[1]*a0[1] + a0[2]*a0[2] + a0[3]*a0[3]
                   + a1[0]*a1[0] + a1[1]*a1[1] + a1[2]*a1[2] + a1[3]*a1[3];

            f32x4 b0 = __builtin_bit_cast(f32x4, wr[c & 1][st * 2]);
            f32x4 b1 = __builtin_bit_cast(f32x4, wr[c & 1][st * 2 + 1]);

            bf16x8 af, bv;
            af[0]=(__bf16)a0[0]; af[1]=(__bf16)a0[1]; af[2]=(__bf16)a0[2]; af[3]=(__bf16)a0[3];
            af[4]=(__bf16)a1[0]; af[5]=(__bf16)a1[1]; af[6]=(__bf16)a1[2]; af[7]=(__bf16)a1[3];
            bv[0]=(__bf16)b0[0]; bv[1]=(__bf16)b0[1]; bv[2]=(__bf16)b0[2]; bv[3]=(__bf16)b0[3];
            bv[4]=(__bf16)b1[0]; bv[5]=(__bf16)b1[1]; bv[6]=(__bf16)b1[2]; bv[7]=(__bf16)b1[3];

            acc = __builtin_amdgcn_mfma_f32_16x16x32_bf16(af, bv, acc, 0, 0, 0);
        }

        __builtin_amdgcn_sched_barrier(0);
        asm volatile("s_barrier" ::: "memory");   // both waves done reading buf
        if (c + 2 < NCH) issue(c + 2);            // safe to overwrite buf[c&1]
    }

    // ---- epilogue: cross-wave combine (k-split partials), RMS, Sinkhorn ----
    float* sc = &lds[0][0][0];
    *(f32x4*)(sc + wave * 256 + lane * 4) = acc;
    sc[512 + wave * 64 + lane] = sumsq;
    asm volatile("s_waitcnt lgkmcnt(0)" ::: "memory");
    __builtin_amdgcn_sched_barrier(0);
    asm volatile("s_barrier" ::: "memory");

    if (wave == 0) {
        f32x4 a0 = *(const f32x4*)(sc + lane * 4);
        f32x4 a1 = *(const f32x4*)(sc + 256 + lane * 4);
        f32x4 cg = a0 + a1;

        float s = sc[512 + lane] + sc[512 + 64 + lane];
        s += __shfl_xor(s, 16);
        s += __shfl_xor(s, 32);          // s = S[r16] in every lane

        const float al = alpha_p[0];
        const float bi = bias[r16];

        float m[4];
#pragma unroll
        for (int r = 0; r < 4; ++r) {
            float Srow  = __shfl(s, kq * 4 + r);   // token row of cg[r]
            float scale = rsqrtf(Srow * (1.0f / DDIM) + 1.1920929e-07f);  // fp32 eps
            m[r] = expf(al * (cg[r] * scale) + bi);
        }

        for (int it = 0; it < SK_ITERS; ++it) {
#pragma unroll
            for (int r = 0; r < 4; ++r) {          // col normalize: sum over i (bits 2,3)
                float t = m[r] + __shfl_xor(m[r], 4);
                t += __shfl_xor(t, 8);
                m[r] = m[r] / (t + 1e-8f);
            }
#pragma unroll
            for (int r = 0; r < 4; ++r) {          // row normalize: sum over j (bits 0,1)
                float t = m[r] + __shfl_xor(m[r], 1);
                t += __shfl_xor(t, 2);
                m[r] = m[r] / (t + 1e-8f);
            }
        }

#pragma unroll
        for (int r = 0; r < 4; ++r)
            out[(size_t)(rowbase + kq * 4 + r) * 16 + r16] = m[r];
    }
}

extern "C" void kernel_launch(void* const* d_in, const int* in_sizes, int n_in,
                              void* d_out, int out_size, void* d_ws, size_t ws_size,
                              hipStream_t stream) {
    const float* x     = (const float*)d_in[0];
    const float* W     = (const float*)d_in[1];
    const float* bias  = (const float*)d_in[2];
    const float* alpha = (const float*)d_in[3];
    float* out = (float*)d_out;

    rsm_kernel<<<dim3(NROWS / 16), dim3(128), 0, stream>>>(x, W, bias, alpha, out);
}

// Round 6
// 53.162 us; speedup vs baseline: 1.4378x; 1.3175x over previous
//
#include <hip/hip_runtime.h>
#include <hip/hip_bf16.h>

#define DDIM 4096
#define NROWS 16384
#define SK_ITERS 20
#define KC 32       // K-floats per chunk per wave
#define NCH 32      // 1024 / KC chunks per wave (K-quarter)

typedef __attribute__((ext_vector_type(8))) __bf16 bf16x8;
typedef __attribute__((ext_vector_type(4))) float f32x4;
typedef __attribute__((ext_vector_type(4))) int   i32x4;

// r3's proven shape, scaled up in occupancy and minus the prologue:
//  - barrier-free main loop, wave-private LDS (4-buffer ring, depth-3 prefetch,
//    issue-at-top, counted per-wave vmcnt waits only)
//  - chunk = 16 rows x 32 K-floats (2 KB): 2 DMA instrs (128B/row windows),
//    W fp32 in the SAME FIFO (2 dwordx4/lane) -> group = 4 vm ops,
//    steady wait vmcnt(12) keeps 3 groups in flight
//  - 32 KB LDS/block + __launch_bounds__(256,4) -> 4 blocks/CU = 16 waves/CU
//  - XOR swizzle: LDS phys granule g holds logical g ^ (row&7); applied as a
//    lane permutation of the source 128B window (linear DMA dest), undone on
//    the ds_read side -> uniform 8 lanes / 4-bank group (b128 structural min)
// k-bijection (A and B identical): k = wave*1024 + c*32 + kq*8 + i.
__global__ __launch_bounds__(256, 4)
void rsm_kernel(const float* __restrict__ x, const float* __restrict__ W,
                const float* __restrict__ bias, const float* __restrict__ alpha_p,
                float* __restrict__ out)
{
    __shared__ __align__(16) float lds[4][4][16][KC];   // [wave][buf][row][k] = 32 KB

    const int tid  = threadIdx.x;
    const int wave = tid >> 6;
    const int lane = tid & 63;
    const int r16  = lane & 15;   // A row-in-tile, W row (output col), C col
    const int kq   = lane >> 4;
    const int z    = r16 & 7;
    const int rowbase = blockIdx.x * 16;

    // DMA instr j stages rows j*8 + (lane>>3); lane writes LDS linearly at
    // (row, phys granule lane&7) <- global granule (lane&7) ^ (lane>>3).
    // (row & 7 == lane>>3 for both j, so the same source pointers serve j=0,1
    //  via a +1KB row offset.)
    const float* sbase[2];
#pragma unroll
    for (int j = 0; j < 2; ++j) {
        int row = j * 8 + (lane >> 3);
        sbase[j] = x + (size_t)(rowbase + row) * DDIM + wave * 1024
                 + (((lane & 7) ^ (lane >> 3)) << 2);
    }

    const float* wq = W + (size_t)r16 * DDIM + wave * 1024 + kq * 8;

    i32x4 wr[4][2];   // W fp32 ring (static idx c&3 after full unroll)

    // group g_c = [2 W dwordx4][2 DMA 1KB] = 4 vm ops
    auto issue = [&](int c) {
        const float* p = wq + c * KC;
        asm volatile(
            "global_load_dwordx4 %0, %2, off\n\t"
            "global_load_dwordx4 %1, %2, off offset:16"
            : "=&v"(wr[c & 3][0]), "=&v"(wr[c & 3][1])
            : "v"(p));
#pragma unroll
        for (int j = 0; j < 2; ++j) {
            __builtin_amdgcn_global_load_lds(
                (const __attribute__((address_space(1))) void*)(sbase[j] + c * KC),
                (__attribute__((address_space(3))) void*)(&lds[wave][c & 3][j * 8][0]),
                16, 0, 0);
        }
    };

    issue(0);
    issue(1);
    issue(2);

    f32x4 acc = {0.f, 0.f, 0.f, 0.f};
    float sumsq = 0.f;

#pragma unroll
    for (int c = 0; c < NCH; ++c) {
        if (c + 3 < NCH) issue(c + 3);
        __builtin_amdgcn_sched_barrier(0);
        if (c + 3 < NCH)      asm volatile("s_waitcnt vmcnt(12)" ::: "memory");
        else if (c == NCH - 3) asm volatile("s_waitcnt vmcnt(8)" ::: "memory");
        else if (c == NCH - 2) asm volatile("s_waitcnt vmcnt(4)" ::: "memory");
        else                   asm volatile("s_waitcnt vmcnt(0)" ::: "memory");
        __builtin_amdgcn_sched_barrier(0);

        const float* arow = &lds[wave][c & 3][r16][0];
        f32x4 a0 = *(const f32x4*)(arow + (((kq * 2    ) ^ z) << 2));
        f32x4 a1 = *(const f32x4*)(arow + (((kq * 2 + 1) ^ z) << 2));

        sumsq += a0[0]*a0[0] + a0[1]*a0[1] + a0[2]*a0[2] + a0[3]*a0[3]
               + a1[0]*a1[0] + a1[1]*a1[1] + a1[2]*a1[2] + a1[3]*a1[3];

        f32x4 b0 = __builtin_bit_cast(f32x4, wr[c & 3][0]);
        f32x4 b1 = __builtin_bit_cast(f32x4, wr[c & 3][1]);

        bf16x8 af, bv;
        af[0]=(__bf16)a0[0]; af[1]=(__bf16)a0[1]; af[2]=(__bf16)a0[2]; af[3]=(__bf16)a0[3];
        af[4]=(__bf16)a1[0]; af[5]=(__bf16)a1[1]; af[6]=(__bf16)a1[2]; af[7]=(__bf16)a1[3];
        bv[0]=(__bf16)b0[0]; bv[1]=(__bf16)b0[1]; bv[2]=(__bf16)b0[2]; bv[3]=(__bf16)b0[3];
        bv[4]=(__bf16)b1[0]; bv[5]=(__bf16)b1[1]; bv[6]=(__bf16)b1[2]; bv[7]=(__bf16)b1[3];

        acc = __builtin_amdgcn_mfma_f32_16x16x32_bf16(af, bv, acc, 0, 0, 0);
    }

    // ---- epilogue: combine K-partials across waves, RMS scale, Sinkhorn ----
    __syncthreads();   // one-time full drain; LDS now reusable
    float* sc = &lds[0][0][0][0];
    *(f32x4*)(sc + wave * 256 + lane * 4) = acc;
    sc[1024 + wave * 64 + lane] = sumsq;
    __syncthreads();

    if (wave == 0) {
        f32x4 cg = *(const f32x4*)(sc + lane * 4);
#pragma unroll
        for (int w = 1; w < 4; ++w)
            cg += *(const f32x4*)(sc + w * 256 + lane * 4);

        float s = sc[1024 + lane] + sc[1024 + 64 + lane]
                + sc[1024 + 128 + lane] + sc[1024 + 192 + lane];
        s += __shfl_xor(s, 16);
        s += __shfl_xor(s, 32);          // s = S[r16] in every lane

        const float al = alpha_p[0];
        const float bi = bias[r16];

        float m[4];
#pragma unroll
        for (int r = 0; r < 4; ++r) {
            float Srow  = __shfl(s, kq * 4 + r);   // token row of cg[r]
            float scale = rsqrtf(Srow * (1.0f / DDIM) + 1.1920929e-07f);  // fp32 eps
            m[r] = expf(al * (cg[r] * scale) + bi);
        }

        for (int it = 0; it < SK_ITERS; ++it) {
#pragma unroll
            for (int r = 0; r < 4; ++r) {          // col normalize: sum over i (bits 2,3)
                float t = m[r] + __shfl_xor(m[r], 4);
                t += __shfl_xor(t, 8);
                m[r] = m[r] / (t + 1e-8f);
            }
#pragma unroll
            for (int r = 0; r < 4; ++r) {          // row normalize: sum over j (bits 0,1)
                float t = m[r] + __shfl_xor(m[r], 1);
                t += __shfl_xor(t, 2);
                m[r] = m[r] / (t + 1e-8f);
            }
        }

#pragma unroll
        for (int r = 0; r < 4; ++r)
            out[(size_t)(rowbase + kq * 4 + r) * 16 + r16] = m[r];
    }
}

extern "C" void kernel_launch(void* const* d_in, const int* in_sizes, int n_in,
                              void* d_out, int out_size, void* d_ws, size_t ws_size,
                              hipStream_t stream) {
    const float* x     = (const float*)d_in[0];
    const float* W     = (const float*)d_in[1];
    const float* bias  = (const float*)d_in[2];
    const float* alpha = (const float*)d_in[3];
    float* out = (float*)d_out;

    rsm_kernel<<<dim3(NROWS / 16), dim3(256), 0, stream>>>(x, W, bias, alpha, out);
}